// Round 3
// baseline (1727.347 us; speedup 1.0000x reference)
//
#include <hip/hip_runtime.h>
#include <cmath>

#define HID 51
#define BATCH 256
#define BLK 384      // 6 waves
#define NR 204       // 4*HID gate rows per matrix
#define MT 13        // M tiles of 16 covering 208 >= 204 permuted rows

typedef _Float16 v8h   __attribute__((ext_vector_type(8)));
typedef float    f32x4 __attribute__((ext_vector_type(4)));

// One block per batch element (grid = 256 = #CUs). One barrier per tick.
// All gate GEMVs run on the MATRIX pipe: 204x51 GEMV = 13 Mtiles x 2 Ktiles
// of v_mfma_f32_16x16x32_f16 with N=1 (every B column carries the same h
// vector, so each column of C is a copy of W.h -- robust to the exact
// lane->k mapping because A and B use the same symmetric placement).
// Gate rows are PERMUTED as row' = 4*u + gate so one C acc quad = (i,f,g,o)
// of unit u = (lane>>4) + 4*m; lanes with (lane&15)==0 write it as one b128
// to pG[u]. Cell lane u then reads ONE float4.
//   wave 0: L0 cell(t=tau)   + Whh1 MFMA -> pGW[0] (intra-wave ring)
//   wave 1: L1 cell(t=tau-2) + Whh  MFMA -> pGW[1]
//   wave 2: L2 cell(t=tau-4) + Whh  MFMA -> pGW[2]
//   wave 3: Wih(L1) . h0(tau-1) -> pGI[0] (parity dbuf)   wave 4: Wih(L2)
//   wave 5: Wl . h2 (1 Mtile) -> obuf ring + 64-wide coalesced flush
// Recurrence stays intra-wave: pGW written and pre-read back BEFORE the
// barrier (same-wave LDS ops are in-order), so tick tau's cell starts with
// its Whh partials already in registers. Cross-wave edges (pGI, h for
// I/O waves) are parity-double-buffered across the single barrier,
// identical to the verified R1 schedule (skew 2/layer, TICKS = T+5).

__device__ __forceinline__ float fsig(float v) {
    return __builtin_amdgcn_rcpf(1.f + __expf(-v));
}
__device__ __forceinline__ float ftanh(float v) {
    const float e = __expf(2.f * v);                 // inf-safe
    return fmaf(-2.f, __builtin_amdgcn_rcpf(e + 1.f), 1.f);
}

__attribute__((amdgpu_waves_per_eu(2, 2)))
__global__ __launch_bounds__(BLK)
void lstm3_kernel(const float* __restrict__ x,
                  const float* __restrict__ Wih1, const float* __restrict__ Whh1,
                  const float* __restrict__ bih1, const float* __restrict__ bhh1,
                  const float* __restrict__ Wih,  const float* __restrict__ Whh,
                  const float* __restrict__ bih,  const float* __restrict__ bhh,
                  const float* __restrict__ Wl,   const float* __restrict__ bl,
                  float* __restrict__ out, int T)
{
    const int b    = blockIdx.x;
    const int tid  = threadIdx.x;
    const int wave = tid >> 6;
    const int lane = tid & 63;
    const int cu   = (lane < HID) ? lane : 0;        // clamped unit index

    __shared__ __align__(16) float xbuf[2048];
    __shared__ __align__(16) int   hrow[3][2][32];   // h fp16, 128B rows, parity dbuf
    __shared__ __align__(16) float pGW[3][4 * 52];   // Whh partials, [unit][i,f,g,o]
    __shared__ __align__(16) float pGI[2][2][4 * 52];// Wih partials, parity dbuf
    __shared__ __align__(16) float obuf[128];        // output ring (2 x 64)

    for (int i = tid; i < T; i += BLK) xbuf[i] = x[(size_t)b * T + i];
    if (tid < 192) ((int*)hrow)[tid] = 0;            // both parities, incl. pads
    for (int i = tid; i < 3 * 208; i += BLK) ((float*)pGW)[i] = 0.f;
    for (int i = tid; i < 4 * 208; i += BLK) ((float*)pGI)[i] = 0.f;

    // ---------------- A fragments (one-time) ----------------
    // Assumed 16x16x32 f16 layout: A row = lane&15, k = (lane>>4)*8 + j.
    v8h A0[MT], A1[MT];
    const int arow = lane & 15;
    const int akb  = (lane >> 4) * 8;
    if (wave < 5) {
        const float* Wsrc =
            (wave == 0) ? Whh1 :
            (wave == 1) ? Whh :
            (wave == 2) ? Whh + (size_t)NR * HID :
            (wave == 3) ? Wih :
                          Wih + (size_t)NR * HID;
        #pragma unroll
        for (int m = 0; m < MT; ++m) {
            const int rp = m * 16 + arow;            // permuted row = 4*u + g
            const int uu = rp >> 2, gg = rp & 3;
            #pragma unroll
            for (int kt = 0; kt < 2; ++kt) {
                v8h f;
                #pragma unroll
                for (int j = 0; j < 8; ++j) {
                    const int k = kt * 32 + akb + j;
                    const float v = (uu < HID && k < HID)
                        ? Wsrc[(size_t)(gg * HID + uu) * HID + k] : 0.f;
                    f[j] = (_Float16)v;
                }
                if (kt == 0) A0[m] = f; else A1[m] = f;
            }
        }
    } else {                                         // O wave: row 0 = Wl
        #pragma unroll
        for (int kt = 0; kt < 2; ++kt) {
            v8h f;
            #pragma unroll
            for (int j = 0; j < 8; ++j) {
                const int k = kt * 32 + akb + j;
                f[j] = (_Float16)((arow == 0 && k < HID) ? Wl[k] : 0.f);
            }
            if (kt == 0) A0[0] = f; else A1[0] = f;
        }
    }

    // ---------------- cell-wave constants ----------------
    float bias4[4] = {0.f, 0.f, 0.f, 0.f};
    float wx4[4]   = {0.f, 0.f, 0.f, 0.f};
    float c_state  = 0.f, outb = 0.f;
    if (wave < 3 && lane < HID) {
        #pragma unroll
        for (int k = 0; k < 4; ++k) {
            const int g = k * HID + lane;
            if (wave == 0) { bias4[k] = bih1[g] + bhh1[g]; wx4[k] = Wih1[g]; }
            else           { const int q = (wave - 1) * NR + g; bias4[k] = bih[q] + bhh[q]; }
        }
    }
    if (wave == 5) outb = bl[0];

    f32x4 pgw = {0.f, 0.f, 0.f, 0.f};                // Whh.h(t-1), pre-read ring
    const f32x4 z = {0.f, 0.f, 0.f, 0.f};
    if (wave < 3) __builtin_amdgcn_s_setprio(1);
    __syncthreads();

    const int TICKS = T + 5;
    for (int tau = 0; tau < TICKS; ++tau) {
        if (wave < 3) {
            // -------- heavy: cell + own-layer Whh GEMV (matrix pipe) --------
            const int l  = wave;
            const int tc = tau - 2 * l;
            f32x4 pgi = z;
            if (l > 0) pgi = *(const f32x4*)&pGI[l - 1][(tau - 1) & 1][4 * cu];
            if ((unsigned)tc < (unsigned)T && lane < HID) {
                float gi  = bias4[0] + pgw[0] + pgi[0];
                float gf  = bias4[1] + pgw[1] + pgi[1];
                float gg_ = bias4[2] + pgw[2] + pgi[2];
                float go  = bias4[3] + pgw[3] + pgi[3];
                if (l == 0) {
                    const float xv = xbuf[tc];       // uniform broadcast
                    gi  = fmaf(wx4[0], xv, gi);
                    gf  = fmaf(wx4[1], xv, gf);
                    gg_ = fmaf(wx4[2], xv, gg_);
                    go  = fmaf(wx4[3], xv, go);
                }
                const float c = fmaf(fsig(gf), c_state, fsig(gi) * ftanh(gg_));
                c_state = c;
                ((_Float16*)&hrow[l][tau & 1][0])[lane] = (_Float16)(fsig(go) * ftanh(c));
            }
            // B fragments from own freshly-written h (same-wave in-order LDS)
            const char* hb = (const char*)&hrow[l][tau & 1][0];
            const v8h bf0 = *(const v8h*)(hb + ((lane >> 4) << 4));
            const v8h bf1 = *(const v8h*)(hb + 64 + ((lane >> 4) << 4));
            f32x4 acc[MT];
            #pragma unroll
            for (int m = 0; m < MT; ++m)
                acc[m] = __builtin_amdgcn_mfma_f32_16x16x32_f16(A1[m], bf1,
                         __builtin_amdgcn_mfma_f32_16x16x32_f16(A0[m], bf0, z, 0, 0, 0),
                         0, 0, 0);
            if ((lane & 15) == 0) {
                const int grp = lane >> 4;
                #pragma unroll
                for (int m = 0; m < MT; ++m)
                    *(f32x4*)&pGW[l][4 * (grp + 4 * m)] = acc[m];
            }
            pgw = *(const f32x4*)&pGW[l][4 * cu];     // pre-read for next tick
        } else if (wave < 5) {
            // -------- I-waves: Wih GEMV from h(prev tick) --------
            const int srcl = wave - 3;
            const char* hb = (const char*)&hrow[srcl][(tau - 1) & 1][0];
            const v8h bf0 = *(const v8h*)(hb + ((lane >> 4) << 4));
            const v8h bf1 = *(const v8h*)(hb + 64 + ((lane >> 4) << 4));
            f32x4 acc[MT];
            #pragma unroll
            for (int m = 0; m < MT; ++m)
                acc[m] = __builtin_amdgcn_mfma_f32_16x16x32_f16(A1[m], bf1,
                         __builtin_amdgcn_mfma_f32_16x16x32_f16(A0[m], bf0, z, 0, 0, 0),
                         0, 0, 0);
            if ((lane & 15) == 0) {
                const int grp = lane >> 4;
                #pragma unroll
                for (int m = 0; m < MT; ++m)
                    *(f32x4*)&pGI[srcl][tau & 1][4 * (grp + 4 * m)] = acc[m];
            }
        } else {
            // -------- O-wave: output row + coalesced flush --------
            const char* hb = (const char*)&hrow[2][(tau - 1) & 1][0];
            const v8h bf0 = *(const v8h*)(hb + ((lane >> 4) << 4));
            const v8h bf1 = *(const v8h*)(hb + 64 + ((lane >> 4) << 4));
            const f32x4 a = __builtin_amdgcn_mfma_f32_16x16x32_f16(A1[0], bf1,
                            __builtin_amdgcn_mfma_f32_16x16x32_f16(A0[0], bf0, z, 0, 0, 0),
                            0, 0, 0);
            const int to = tau - 5;
            if (lane == 0 && (unsigned)to < (unsigned)T)
                obuf[to & 127] = a[0] + outb;        // C row0 col0 lives in lane 0
            if ((tau & 63) == 4 && tau >= 68) {
                const int t0 = tau - 68;             // multiple of 64
                out[(size_t)b * T + t0 + lane] = obuf[(t0 & 64) + lane];
            }
        }
        __syncthreads();                             // the ONLY barrier per tick
    }
}

extern "C" void kernel_launch(void* const* d_in, const int* in_sizes, int n_in,
                              void* d_out, int out_size, void* d_ws, size_t ws_size,
                              hipStream_t stream) {
    const float* x    = (const float*)d_in[0];
    const float* Wih1 = (const float*)d_in[1];
    const float* Whh1 = (const float*)d_in[2];
    const float* bih1 = (const float*)d_in[3];
    const float* bhh1 = (const float*)d_in[4];
    const float* Wih  = (const float*)d_in[5];
    const float* Whh  = (const float*)d_in[6];
    const float* bih  = (const float*)d_in[7];
    const float* bhh  = (const float*)d_in[8];
    const float* Wl   = (const float*)d_in[9];
    const float* bl   = (const float*)d_in[10];
    float* out = (float*)d_out;

    const int T = in_sizes[0] / BATCH;   // 2048 (flush assumes T % 64 == 0)
    lstm3_kernel<<<BATCH, BLK, 0, stream>>>(x, Wih1, Whh1, bih1, bhh1,
                                            Wih, Whh, bih, bhh, Wl, bl, out, T);
}

// Round 4
// 1462.321 us; speedup vs baseline: 1.1812x; 1.1812x over previous
//
#include <hip/hip_runtime.h>
#include <cmath>

#define HID 51
#define BATCH 256
#define BLK 384      // 6 waves
#define NR 204       // 4*HID gate rows per matrix
#define MT 13        // M tiles of 16 covering 208 >= 204 permuted rows

typedef _Float16 v8h   __attribute__((ext_vector_type(8)));
typedef float    f32x4 __attribute__((ext_vector_type(4)));

// One block per batch element (grid = 256 = #CUs). One barrier per tick.
// GEMVs on the matrix pipe (layout validated by R3: A row=lane&15,
// k=(lane>>4)*8+j; C col=lane&15, row=(lane>>4)*4+reg; B broadcast).
// Gate rows permuted row'=4u+gate, so lane 16*grp+c holds the full
// (i,f,g,o) quad of unit u=4c+grp in acc[c]. KEY CHANGE vs R3: the cell
// for unit u runs IN that lane (select acc[cm] via unrolled cndmask tree,
// compile-time indices only) -- Whh partials never leave registers, no
// pGW buffer, no accvgpr->LDS shuttle. I-waves write pGI as one quad per
// unit (13 masked b128 stores, 4 lanes each); heavy reads one b128/lane.
//   wave 0: L0 cell(t=tau)   + Whh1 MFMA (acc persistent)
//   wave 1: L1 cell(t=tau-2) + Whh MFMA
//   wave 2: L2 cell(t=tau-4) + Whh MFMA
//   wave 3: Wih(L1).h0(tau-1) -> pGI[0][tau&1]   wave 4: Wih(L2) -> pGI[1]
//   wave 5: Wl.h2 (tile 0 only) -> obuf ring + 64-wide coalesced flush
// Schedule identical to R3 (verified): heavy l at tick tau does t=tau-2l;
// I-waves read h[(tau-1)&1], write pGI[tau&1]; heavy reads pGI[(tau-1)&1].
// TICKS = T+5; flush at (tau&63)==4, tau>=68.

__device__ __forceinline__ float fsig(float v) {
    return __builtin_amdgcn_rcpf(1.f + __expf(-v));
}
__device__ __forceinline__ float ftanh(float v) {
    const float e = __expf(2.f * v);                 // inf-safe
    return fmaf(-2.f, __builtin_amdgcn_rcpf(e + 1.f), 1.f);
}

__attribute__((amdgpu_waves_per_eu(2, 2)))
__global__ __launch_bounds__(BLK)
void lstm3_kernel(const float* __restrict__ x,
                  const float* __restrict__ Wih1, const float* __restrict__ Whh1,
                  const float* __restrict__ bih1, const float* __restrict__ bhh1,
                  const float* __restrict__ Wih,  const float* __restrict__ Whh,
                  const float* __restrict__ bih,  const float* __restrict__ bhh,
                  const float* __restrict__ Wl,   const float* __restrict__ bl,
                  float* __restrict__ out, int T)
{
    const int b    = blockIdx.x;
    const int tid  = threadIdx.x;
    const int wave = tid >> 6;
    const int lane = tid & 63;

    __shared__ __align__(16) float xbuf[2048];
    __shared__ __align__(16) int   hrow[3][2][32];   // h fp16, 128B rows, parity dbuf
    __shared__ __align__(16) f32x4 pGI[2][2][64];    // Wih partial quads per unit
    __shared__ __align__(16) float obuf[128];        // output ring (2 x 64)

    const f32x4 z = {0.f, 0.f, 0.f, 0.f};

    for (int i = tid; i < T; i += BLK) xbuf[i] = x[(size_t)b * T + i];
    if (tid < 192) ((int*)hrow)[tid] = 0;            // both parities, incl. pads
    for (int i = tid; i < 256; i += BLK) ((f32x4*)pGI)[i] = z;

    // ---------------- A fragments (one-time; validated in R3) ----------------
    v8h A0[MT], A1[MT];
    const int arow = lane & 15;
    const int akb  = (lane >> 4) * 8;
    if (wave < 5) {
        const float* Wsrc =
            (wave == 0) ? Whh1 :
            (wave == 1) ? Whh :
            (wave == 2) ? Whh + (size_t)NR * HID :
            (wave == 3) ? Wih :
                          Wih + (size_t)NR * HID;
        #pragma unroll
        for (int m = 0; m < MT; ++m) {
            const int rp = m * 16 + arow;            // permuted row = 4*u + g
            const int uu = rp >> 2, gg = rp & 3;
            #pragma unroll
            for (int kt = 0; kt < 2; ++kt) {
                v8h f;
                #pragma unroll
                for (int j = 0; j < 8; ++j) {
                    const int k = kt * 32 + akb + j;
                    const float v = (uu < HID && k < HID)
                        ? Wsrc[(size_t)(gg * HID + uu) * HID + k] : 0.f;
                    f[j] = (_Float16)v;
                }
                if (kt == 0) A0[m] = f; else A1[m] = f;
            }
        }
    } else {                                         // O wave: row 0 = Wl
        #pragma unroll
        for (int kt = 0; kt < 2; ++kt) {
            v8h f;
            #pragma unroll
            for (int j = 0; j < 8; ++j) {
                const int k = kt * 32 + akb + j;
                f[j] = (_Float16)((arow == 0 && k < HID) ? Wl[k] : 0.f);
            }
            if (kt == 0) A0[0] = f; else A1[0] = f;
        }
    }

    // ---------------- cell-lane constants ----------------
    const int cm   = lane & 15;                      // tile index this lane owns
    const int cgrp = lane >> 4;
    const int cu   = 4 * cm + cgrp;                  // unit (<=63, valid <51)
    const bool is_cell = (wave < 3) && (cm < MT) && (cu < HID);
    float bias4[4] = {0.f, 0.f, 0.f, 0.f};
    float wx4[4]   = {0.f, 0.f, 0.f, 0.f};
    float c_state  = 0.f, outb = 0.f;
    if (is_cell) {
        #pragma unroll
        for (int k = 0; k < 4; ++k) {
            const int g = k * HID + cu;
            if (wave == 0) { bias4[k] = bih1[g] + bhh1[g]; wx4[k] = Wih1[g]; }
            else           { const int q = (wave - 1) * NR + g; bias4[k] = bih[q] + bhh[q]; }
        }
    }
    if (wave == 5) outb = bl[0];

    f32x4 acc[MT];                                   // heavy: Whh.h quads, persistent
    #pragma unroll
    for (int m = 0; m < MT; ++m) acc[m] = z;         // Whh.h(-1) = 0

    if (wave < 3) __builtin_amdgcn_s_setprio(1);
    __syncthreads();

    const int TICKS = T + 5;
    for (int tau = 0; tau < TICKS; ++tau) {
        if (wave < 3) {
            // -------- heavy: in-register combine + cell + Whh MFMA --------
            const int l  = wave;
            const int tc = tau - 2 * l;
            f32x4 pgi = z;
            if (l > 0) pgi = pGI[l - 1][(tau - 1) & 1][cu];   // one b128/lane
            f32x4 wh = acc[0];                       // select acc[cm], unrolled
            #pragma unroll
            for (int m = 1; m < MT; ++m) if (cm == m) wh = acc[m];
            if ((unsigned)tc < (unsigned)T && is_cell) {
                float gi  = bias4[0] + wh[0] + pgi[0];
                float gf  = bias4[1] + wh[1] + pgi[1];
                float gg_ = bias4[2] + wh[2] + pgi[2];
                float go  = bias4[3] + wh[3] + pgi[3];
                if (l == 0) {
                    const float xv = xbuf[tc];       // uniform broadcast
                    gi  = fmaf(wx4[0], xv, gi);
                    gf  = fmaf(wx4[1], xv, gf);
                    gg_ = fmaf(wx4[2], xv, gg_);
                    go  = fmaf(wx4[3], xv, go);
                }
                const float c = fmaf(fsig(gf), c_state, fsig(gi) * ftanh(gg_));
                c_state = c;
                ((_Float16*)&hrow[l][tau & 1][0])[cu] = (_Float16)(fsig(go) * ftanh(c));
            }
            // B frags from own freshly-written h (same-wave LDS ordering)
            const char* hb = (const char*)&hrow[l][tau & 1][0];
            const v8h bf0 = *(const v8h*)(hb + ((lane >> 4) << 4));
            const v8h bf1 = *(const v8h*)(hb + 64 + ((lane >> 4) << 4));
            #pragma unroll
            for (int m = 0; m < MT; ++m) {
                acc[m] = __builtin_amdgcn_mfma_f32_16x16x32_f16(A0[m], bf0, z, 0, 0, 0);
                acc[m] = __builtin_amdgcn_mfma_f32_16x16x32_f16(A1[m], bf1, acc[m], 0, 0, 0);
            }
        } else if (wave < 5) {
            // -------- I-waves: Wih GEMV, one quad per unit to pGI --------
            const int srcl = wave - 3;
            const char* hb = (const char*)&hrow[srcl][(tau - 1) & 1][0];
            const v8h bf0 = *(const v8h*)(hb + ((lane >> 4) << 4));
            const v8h bf1 = *(const v8h*)(hb + 64 + ((lane >> 4) << 4));
            f32x4 ia[MT];
            #pragma unroll
            for (int m = 0; m < MT; ++m) {
                ia[m] = __builtin_amdgcn_mfma_f32_16x16x32_f16(A0[m], bf0, z, 0, 0, 0);
                ia[m] = __builtin_amdgcn_mfma_f32_16x16x32_f16(A1[m], bf1, ia[m], 0, 0, 0);
            }
            #pragma unroll
            for (int m = 0; m < MT; ++m)             // lane 16*grp+m owns unit 4m+grp
                if (cm == m) pGI[srcl][tau & 1][4 * m + cgrp] = ia[m];
        } else {
            // -------- O-wave: output row (tile 0) + coalesced flush --------
            const char* hb = (const char*)&hrow[2][(tau - 1) & 1][0];
            const v8h bf0 = *(const v8h*)(hb + ((lane >> 4) << 4));
            const v8h bf1 = *(const v8h*)(hb + 64 + ((lane >> 4) << 4));
            f32x4 a = __builtin_amdgcn_mfma_f32_16x16x32_f16(A0[0], bf0, z, 0, 0, 0);
            a = __builtin_amdgcn_mfma_f32_16x16x32_f16(A1[0], bf1, a, 0, 0, 0);
            const int to = tau - 5;
            if (lane == 0 && (unsigned)to < (unsigned)T)
                obuf[to & 127] = a[0] + outb;        // C row0 col0 in lane 0 reg 0
            if ((tau & 63) == 4 && tau >= 68) {
                const int t0 = tau - 68;             // multiple of 64
                out[(size_t)b * T + t0 + lane] = obuf[(t0 & 64) + lane];
            }
        }
        __syncthreads();                             // the ONLY barrier per tick
    }
}

extern "C" void kernel_launch(void* const* d_in, const int* in_sizes, int n_in,
                              void* d_out, int out_size, void* d_ws, size_t ws_size,
                              hipStream_t stream) {
    const float* x    = (const float*)d_in[0];
    const float* Wih1 = (const float*)d_in[1];
    const float* Whh1 = (const float*)d_in[2];
    const float* bih1 = (const float*)d_in[3];
    const float* bhh1 = (const float*)d_in[4];
    const float* Wih  = (const float*)d_in[5];
    const float* Whh  = (const float*)d_in[6];
    const float* bih  = (const float*)d_in[7];
    const float* bhh  = (const float*)d_in[8];
    const float* Wl   = (const float*)d_in[9];
    const float* bl   = (const float*)d_in[10];
    float* out = (float*)d_out;

    const int T = in_sizes[0] / BATCH;   // 2048 (flush assumes T % 64 == 0)
    lstm3_kernel<<<BATCH, BLK, 0, stream>>>(x, Wih1, Whh1, bih1, bhh1,
                                            Wih, Whh, bih, bhh, Wl, bl, out, T);
}